// Round 3
// baseline (102.205 us; speedup 1.0000x reference)
//
#include <hip/hip_runtime.h>
#include <math.h>

#define B_ 512
#define I_ 512
#define O_ 512
#define IO_ (I_*O_)
#define BO_ (B_*O_)

// main-kernel tiling
#define NO 16                 // o per block (4 per wave)
#define NB 64                 // b per block (= lanes)
#define NI 64                 // i-range per block
#define ISP (I_/NI)           // 8 i-splits
#define NSEG 256              // column-stat segments

#define SQH   0.84932181f     // sqrt(0.5*log2(e))
#define MQ    -1.3862944f     // -(2*ln2):  t^2 = (-h^2) * MQ
#define NORM_ 0.8673250705840775f
#define BN_EPS 1e-5f

#define K_EXP  (-0.72134752044448170f)   // fallback path
#define TB 64
#define TO 16
#define KI 16
#define NCH (I_/KI)
#define LXS (TB + 4)

#if defined(__has_builtin)
#if __has_builtin(__builtin_amdgcn_exp2f)
#define EXP2F(v) __builtin_amdgcn_exp2f(v)
#endif
#endif
#ifndef EXP2F
#define EXP2F(v) exp2f(v)
#endif

// ---------------------------------------------------------------------------
// Kernel 0: transpose-pack params into o-major planes.
//   Pb[o][i] = bias[i][o]
//   Pc[o][i] = SQH / scale[i][o]
//   Pw[o][i] = NORM * weight[i][o]
// ---------------------------------------------------------------------------
__global__ __launch_bounds__(256) void pack_t(
    const float* __restrict__ scale, const float* __restrict__ bias,
    const float* __restrict__ weight,
    float* __restrict__ Pb, float* __restrict__ Pc, float* __restrict__ Pw)
{
    __shared__ float T[64][68];          // [o_local][i_local], padded rows (16B aligned)
    const int t   = threadIdx.x;
    const int i0  = blockIdx.x * 64;
    const int o0  = blockIdx.y * 64;
    const int ir  = t >> 4;              // 0..15
    const int c4  = (t & 15) * 4;        // 0..60

    #pragma unroll
    for (int arr = 0; arr < 3; ++arr) {
        const float* src = (arr == 0) ? bias : ((arr == 1) ? scale : weight);
        float*       dst = (arr == 0) ? Pb   : ((arr == 1) ? Pc    : Pw);
        __syncthreads();                 // protect T reuse across arrays
        #pragma unroll
        for (int p = 0; p < 4; ++p) {
            const int i = i0 + ir + p * 16;
            float4 v = *reinterpret_cast<const float4*>(&src[(size_t)i * O_ + o0 + c4]);
            if (arr == 1) {
                v.x = SQH / v.x; v.y = SQH / v.y; v.z = SQH / v.z; v.w = SQH / v.w;
            } else if (arr == 2) {
                v.x *= NORM_; v.y *= NORM_; v.z *= NORM_; v.w *= NORM_;
            }
            T[c4 + 0][ir + p * 16] = v.x;
            T[c4 + 1][ir + p * 16] = v.y;
            T[c4 + 2][ir + p * 16] = v.z;
            T[c4 + 3][ir + p * 16] = v.w;
        }
        __syncthreads();
        #pragma unroll
        for (int p = 0; p < 4; ++p) {
            const int ol = ir + p * 16;
            const float4 v = *reinterpret_cast<const float4*>(&T[ol][c4]);
            *reinterpret_cast<float4*>(&dst[(size_t)(o0 + ol) * I_ + i0 + c4]) = v;
        }
    }
}

// ---------------------------------------------------------------------------
// Kernel 1: partial KAN sums. Wave-uniform o (4 o's per wave) => params ride
// the scalar pipe (s_load); x chunk lives in 16 VGPRs, reused across 4 o's.
// Inner loop: 6 VALU + 1 transcendental per eval, no vector-memory ops.
// ---------------------------------------------------------------------------
__global__ __launch_bounds__(256, 8) void kan_s(
    const float* __restrict__ x,
    const float* __restrict__ Pb, const float* __restrict__ Pc,
    const float* __restrict__ Pw, float* __restrict__ pY)
{
    __shared__ float Lx[NB][20];         // x chunk, 80B rows: balanced bank groups

    const int t    = threadIdx.x;
    const int lane = t & 63;
    const int wvu  = __builtin_amdgcn_readfirstlane(t >> 6);  // wave id as SGPR
    const int o0   = blockIdx.x * NO;
    const int b0   = blockIdx.y * NB;
    const int z0   = blockIdx.z * NI;
    const int ow   = o0 + wvu * 4;       // this wave's first o (uniform)
    const int sr   = t >> 2;             // staging row (b)
    const int sq   = t & 3;              // staging i-quarter

    float acc[4] = {0.f, 0.f, 0.f, 0.f};

    for (int ch = 0; ch < NI / 16; ++ch) {
        const int i0 = z0 + ch * 16;
        const float4 xv = *reinterpret_cast<const float4*>(
            &x[(size_t)(b0 + sr) * I_ + i0 + sq * 4]);
        __syncthreads();                 // previous chunk fully consumed
        *reinterpret_cast<float4*>(&Lx[sr][sq * 4]) = xv;
        __syncthreads();                 // staging visible

        float xr[16];
        #pragma unroll
        for (int k = 0; k < 4; ++k) {
            const float4 v = *reinterpret_cast<const float4*>(&Lx[lane][k * 4]);
            xr[k * 4 + 0] = v.x; xr[k * 4 + 1] = v.y;
            xr[k * 4 + 2] = v.z; xr[k * 4 + 3] = v.w;
        }

        #pragma unroll
        for (int oj = 0; oj < 4; ++oj) {
            const size_t pofs = (size_t)(ow + oj) * I_ + i0;   // uniform
            const float* __restrict__ pb = Pb + pofs;
            const float* __restrict__ pc = Pc + pofs;
            const float* __restrict__ pw = Pw + pofs;
            float a = acc[oj];
            #pragma unroll
            for (int ii = 0; ii < 16; ++ii) {
                const float dd  = xr[ii] - pb[ii];     // VOP3, 1 SGPR
                const float hh  = dd * pc[ii];         // 1 SGPR
                const float h2n = -hh * hh;            // neg modifier
                const float ee  = EXP2F(h2n);          // trans: e^{-t^2/2}
                const float t2  = h2n * MQ;            // = t^2 (literal)
                const float gg  = fmaf(t2, pw[ii], -pw[ii]);  // same SGPR twice: legal
                a = fmaf(gg, ee, a);
            }
            acc[oj] = a;
        }
    }

    const float4 outv = make_float4(acc[0], acc[1], acc[2], acc[3]);
    *reinterpret_cast<float4*>(
        &pY[((size_t)blockIdx.z * B_ + b0 + lane) * O_ + ow]) = outv;
}

// ---------------------------------------------------------------------------
// Kernel 2: sum 8 i-partials -> y; per-(2-row, o) column partial stats.
// ---------------------------------------------------------------------------
__global__ __launch_bounds__(256) void comb_s(
    const float* __restrict__ pY, float* __restrict__ y,
    float* __restrict__ cs, float* __restrict__ cs2)
{
    const int t    = threadIdx.x;
    const int oq   = t & 127;            // o-quad
    const int half = t >> 7;             // 0/1
    const int bb   = blockIdx.x * 4 + half * 2;

    float sx = 0.f, sy = 0.f, sz = 0.f, sw = 0.f;
    float qx = 0.f, qy = 0.f, qz = 0.f, qw = 0.f;

    #pragma unroll
    for (int r = 0; r < 2; ++r) {
        const int b = bb + r;
        float vx = 0.f, vy = 0.f, vz = 0.f, vw = 0.f;
        #pragma unroll
        for (int k = 0; k < ISP; ++k) {
            const float4 p = *reinterpret_cast<const float4*>(
                &pY[(size_t)k * BO_ + (size_t)b * O_ + oq * 4]);
            vx += p.x; vy += p.y; vz += p.z; vw += p.w;
        }
        *reinterpret_cast<float4*>(&y[(size_t)b * O_ + oq * 4]) =
            make_float4(vx, vy, vz, vw);
        sx += vx; sy += vy; sz += vz; sw += vw;
        qx += vx * vx; qy += vy * vy; qz += vz * vz; qw += vw * vw;
    }

    const int seg = blockIdx.x * 2 + half;
    *reinterpret_cast<float4*>(&cs [(size_t)seg * O_ + oq * 4]) = make_float4(sx, sy, sz, sw);
    *reinterpret_cast<float4*>(&cs2[(size_t)seg * O_ + oq * 4]) = make_float4(qx, qy, qz, qw);
}

// ---------------------------------------------------------------------------
// Kernel 3: finalize BN, normalize y in place.
// ---------------------------------------------------------------------------
__global__ __launch_bounds__(256) void bn_f(
    const float* __restrict__ cs, const float* __restrict__ cs2,
    const float* __restrict__ gamma, const float* __restrict__ beta,
    float* __restrict__ y)
{
    const int o = blockIdx.x * 256 + threadIdx.x;
    float s = 0.f, s2 = 0.f;
    #pragma unroll 8
    for (int k = 0; k < NSEG; ++k) {
        s  += cs [(size_t)k * O_ + o];
        s2 += cs2[(size_t)k * O_ + o];
    }
    const float mean = s * (1.0f / B_);
    const float var  = s2 * (1.0f / B_) - mean * mean;
    const float inv  = rsqrtf(var + BN_EPS);
    const float a = gamma[o] * inv;
    const float c = fmaf(-mean, a, beta[o]);

    const int bstart = blockIdx.y * 32;
    #pragma unroll
    for (int b = bstart; b < bstart + 32; ++b) {
        const size_t idx = (size_t)b * O_ + o;
        y[idx] = fmaf(y[idx], a, c);
    }
}

// ---------------------------------------------------------------------------
// Fallback path (Round-1 kernels, 32 KB ws) — used only if ws too small.
// ---------------------------------------------------------------------------
__global__ __launch_bounds__(256) void kan_main(
    const float* __restrict__ x, const float* __restrict__ scale,
    const float* __restrict__ bias, const float* __restrict__ weight,
    float* __restrict__ y, float* __restrict__ psum, float* __restrict__ psumsq)
{
    __shared__ float LxF[KI][LXS];
    __shared__ float Lp[KI][TO][4];
    __shared__ float Rs[2][TB/4][TO];

    const int t   = threadIdx.x;
    const int to  = t & (TO - 1);
    const int tb4 = t >> 4;
    const int o0  = blockIdx.x * TO;
    const int b0  = blockIdx.y * TB;
    const int lb = t >> 2;
    const int lq = t & 3;
    const int li = t >> 4;
    const int lo = t & 15;

    float acc0 = 0.f, acc1 = 0.f, acc2 = 0.f, acc3 = 0.f;

    for (int ch = 0; ch < NCH; ++ch) {
        const int i0 = ch * KI;
        const float4 xv = *reinterpret_cast<const float4*>(&x[(b0 + lb) * I_ + i0 + lq * 4]);
        const int pidx = (i0 + li) * O_ + o0 + lo;
        const float sc = scale[pidx];
        const float bi = bias[pidx];
        const float w  = weight[pidx];

        __syncthreads();
        LxF[lq * 4 + 0][lb] = xv.x;
        LxF[lq * 4 + 1][lb] = xv.y;
        LxF[lq * 4 + 2][lb] = xv.z;
        LxF[lq * 4 + 3][lb] = xv.w;
        const float rs = __builtin_amdgcn_rcpf(sc);
        Lp[li][lo][0] = rs;
        Lp[li][lo][1] = bi * rs;
        Lp[li][lo][2] = w;
        __syncthreads();

        #pragma unroll
        for (int ii = 0; ii < KI; ++ii) {
            const float4 p  = *reinterpret_cast<const float4*>(&Lp[ii][to][0]);
            const float4 xx = *reinterpret_cast<const float4*>(&LxF[ii][tb4 * 4]);
            {
                const float tt = fmaf(xx.x, p.x, -p.y);
                const float t2 = tt * tt;
                const float e  = EXP2F(t2 * K_EXP);
                const float g  = fmaf(t2, p.z, -p.z);
                acc0 = fmaf(g, e, acc0);
            }
            {
                const float tt = fmaf(xx.y, p.x, -p.y);
                const float t2 = tt * tt;
                const float e  = EXP2F(t2 * K_EXP);
                const float g  = fmaf(t2, p.z, -p.z);
                acc1 = fmaf(g, e, acc1);
            }
            {
                const float tt = fmaf(xx.z, p.x, -p.y);
                const float t2 = tt * tt;
                const float e  = EXP2F(t2 * K_EXP);
                const float g  = fmaf(t2, p.z, -p.z);
                acc2 = fmaf(g, e, acc2);
            }
            {
                const float tt = fmaf(xx.w, p.x, -p.y);
                const float t2 = tt * tt;
                const float e  = EXP2F(t2 * K_EXP);
                const float g  = fmaf(t2, p.z, -p.z);
                acc3 = fmaf(g, e, acc3);
            }
        }
    }

    const float y0 = NORM_ * acc0;
    const float y1 = NORM_ * acc1;
    const float y2 = NORM_ * acc2;
    const float y3 = NORM_ * acc3;

    const int brow = b0 + tb4 * 4;
    y[(brow + 0) * O_ + o0 + to] = y0;
    y[(brow + 1) * O_ + o0 + to] = y1;
    y[(brow + 2) * O_ + o0 + to] = y2;
    y[(brow + 3) * O_ + o0 + to] = y3;

    Rs[0][tb4][to] = y0 + y1 + y2 + y3;
    Rs[1][tb4][to] = y0 * y0 + y1 * y1 + y2 * y2 + y3 * y3;
    __syncthreads();
    if (t < TO) {
        float s = 0.f, s2 = 0.f;
        #pragma unroll
        for (int k = 0; k < TB / 4; ++k) {
            s  += Rs[0][k][t];
            s2 += Rs[1][k][t];
        }
        psum  [blockIdx.y * O_ + o0 + t] = s;
        psumsq[blockIdx.y * O_ + o0 + t] = s2;
    }
}

__global__ __launch_bounds__(256) void bn_apply(
    const float* __restrict__ psum, const float* __restrict__ psumsq,
    const float* __restrict__ gamma, const float* __restrict__ beta,
    float* __restrict__ y)
{
    const int o = blockIdx.x * 256 + threadIdx.x;
    float s = 0.f, s2 = 0.f;
    #pragma unroll
    for (int k = 0; k < B_ / TB; ++k) {
        s  += psum  [k * O_ + o];
        s2 += psumsq[k * O_ + o];
    }
    const float mean = s * (1.0f / B_);
    const float var  = s2 * (1.0f / B_) - mean * mean;
    const float inv  = rsqrtf(var + BN_EPS);
    const float a = gamma[o] * inv;
    const float c = fmaf(-mean, a, beta[o]);

    const int bstart = blockIdx.y * 16;
    #pragma unroll
    for (int b = bstart; b < bstart + 16; ++b) {
        const int idx = b * O_ + o;
        y[idx] = fmaf(y[idx], a, c);
    }
}

// ---------------------------------------------------------------------------

extern "C" void kernel_launch(void* const* d_in, const int* in_sizes, int n_in,
                              void* d_out, int out_size, void* d_ws, size_t ws_size,
                              hipStream_t stream) {
    const float* x      = (const float*)d_in[0];
    const float* scale  = (const float*)d_in[1];
    const float* bias   = (const float*)d_in[2];
    const float* weight = (const float*)d_in[3];
    const float* gamma  = (const float*)d_in[4];
    const float* beta   = (const float*)d_in[5];
    float* out = (float*)d_out;

    const size_t planes_b = 3 * (size_t)IO_ * sizeof(float);          // 3 MB
    const size_t pY_b     = (size_t)ISP * BO_ * sizeof(float);        // 8 MB
    const size_t cs_b     = (size_t)NSEG * O_ * sizeof(float);        // 512 KB
    const size_t need = planes_b + pY_b + 2 * cs_b;

    if (ws_size >= need) {
        float* Pb  = (float*)d_ws;
        float* Pc  = Pb + IO_;
        float* Pw  = Pc + IO_;
        float* pY  = Pw + IO_;
        float* cs  = pY + (size_t)ISP * BO_;
        float* cs2 = cs + (size_t)NSEG * O_;

        dim3 gp(I_ / 64, O_ / 64);                 // (8, 8)
        pack_t<<<gp, 256, 0, stream>>>(scale, bias, weight, Pb, Pc, Pw);

        dim3 g1(O_ / NO, B_ / NB, ISP);            // (32, 8, 8) = 2048 blocks
        kan_s<<<g1, 256, 0, stream>>>(x, Pb, Pc, Pw, pY);

        comb_s<<<B_ / 4, 256, 0, stream>>>(pY, out, cs, cs2);   // 128 blocks

        dim3 g3(O_ / 256, B_ / 32);                // (2, 16)
        bn_f<<<g3, 256, 0, stream>>>(cs, cs2, gamma, beta, out);
    } else {
        float* psum   = (float*)d_ws;
        float* psumsq = psum + (B_ / TB) * O_;

        dim3 g1(O_ / TO, B_ / TB);
        kan_main<<<g1, 256, 0, stream>>>(x, scale, bias, weight, out, psum, psumsq);

        dim3 g2(O_ / 256, B_ / 16);
        bn_apply<<<g2, 256, 0, stream>>>(psum, psumsq, gamma, beta, out);
    }
}

// Round 4
// 41.976 us; speedup vs baseline: 2.4348x; 2.4348x over previous
//
#include <hip/hip_runtime.h>
#include <math.h>

#define B_ 512
#define I_ 512
#define O_ 512
#define BO_ (B_*O_)

#define TB 64                  // b per block
#define TO 16                  // o per block
#define KI 16                  // i per chunk
#define ISPLIT 4               // i-range splits
#define NI (I_/ISPLIT)         // 128 i per block
#define LXS (TB + 4)           // padded x rows
#define NCH (I_/KI)            // fallback chunk count

#define K_EXP  (-0.72134752044448170f)   // -0.5 * log2(e)
#define NORM_  (0.86732507058407750f)    // 2 / (sqrt(3) * pi^0.25)
#define BN_EPS (1e-5f)

#if defined(__has_builtin)
#if __has_builtin(__builtin_amdgcn_exp2f)
#define EXP2F(v) __builtin_amdgcn_exp2f(v)
#endif
#endif
#ifndef EXP2F
#define EXP2F(v) exp2f(v)
#endif

// ---------------------------------------------------------------------------
// K1: partial KAN sums over i-range. Round-1 LDS staging (params+x), 1024
// blocks, XCD-chunked swizzle so each XCD touches only 4 o-tiles of params.
// ---------------------------------------------------------------------------
__global__ __launch_bounds__(256) void kan4(
    const float* __restrict__ x, const float* __restrict__ scale,
    const float* __restrict__ bias, const float* __restrict__ weight,
    float* __restrict__ pY)
{
    __shared__ float Lx[KI][LXS];      // x transposed: [i_local][b_local]
    __shared__ float Lp[KI][TO][4];    // {rs, bias*rs, w, pad}

    // swizzle: fid -> (o_tile, b_tile, i_split) so each XCD (fid&7) owns
    // 4 consecutive o-tiles across all (b,z): params stay L2-resident.
    const int fid = blockIdx.x;
    const int xcd = fid & 7;
    const int seq = fid >> 3;              // 0..127
    const int ot  = xcd * 4 + (seq & 3);   // 0..31
    const int by  = (seq >> 2) & 7;        // 0..7
    const int iz  = seq >> 5;              // 0..3

    const int o0 = ot * TO;
    const int b0 = by * TB;
    const int z0 = iz * NI;

    const int t   = threadIdx.x;
    const int to  = t & (TO - 1);      // o within tile
    const int tb4 = t >> 4;            // 0..15, owns b_local = tb4*4 .. +3
    const int lb  = t >> 2;            // x staging row (b)
    const int lq  = t & 3;             // x staging i-quarter
    const int li  = t >> 4;            // param staging i
    const int lo  = t & 15;            // param staging o

    float acc0 = 0.f, acc1 = 0.f, acc2 = 0.f, acc3 = 0.f;

    for (int ch = 0; ch < NI / KI; ++ch) {
        const int i0 = z0 + ch * KI;
        // issue global loads before the barrier so they overlap the wait
        const float4 xv = *reinterpret_cast<const float4*>(
            &x[(size_t)(b0 + lb) * I_ + i0 + lq * 4]);
        const int pidx = (i0 + li) * O_ + o0 + lo;
        const float sc = scale[pidx];
        const float bi = bias[pidx];
        const float w  = weight[pidx];

        __syncthreads();               // previous chunk fully consumed
        Lx[lq * 4 + 0][lb] = xv.x;
        Lx[lq * 4 + 1][lb] = xv.y;
        Lx[lq * 4 + 2][lb] = xv.z;
        Lx[lq * 4 + 3][lb] = xv.w;
        const float rs = __builtin_amdgcn_rcpf(sc);
        Lp[li][lo][0] = rs;
        Lp[li][lo][1] = bi * rs;
        Lp[li][lo][2] = w;
        __syncthreads();               // staging visible

        #pragma unroll
        for (int ii = 0; ii < KI; ++ii) {
            const float4 p  = *reinterpret_cast<const float4*>(&Lp[ii][to][0]);
            const float4 xx = *reinterpret_cast<const float4*>(&Lx[ii][tb4 * 4]);
            {
                const float tt = fmaf(xx.x, p.x, -p.y);
                const float t2 = tt * tt;
                const float e  = EXP2F(t2 * K_EXP);
                const float g  = fmaf(t2, p.z, -p.z);
                acc0 = fmaf(g, e, acc0);
            }
            {
                const float tt = fmaf(xx.y, p.x, -p.y);
                const float t2 = tt * tt;
                const float e  = EXP2F(t2 * K_EXP);
                const float g  = fmaf(t2, p.z, -p.z);
                acc1 = fmaf(g, e, acc1);
            }
            {
                const float tt = fmaf(xx.z, p.x, -p.y);
                const float t2 = tt * tt;
                const float e  = EXP2F(t2 * K_EXP);
                const float g  = fmaf(t2, p.z, -p.z);
                acc2 = fmaf(g, e, acc2);
            }
            {
                const float tt = fmaf(xx.w, p.x, -p.y);
                const float t2 = tt * tt;
                const float e  = EXP2F(t2 * K_EXP);
                const float g  = fmaf(t2, p.z, -p.z);
                acc3 = fmaf(g, e, acc3);
            }
        }
    }

    float* yp = pY + (size_t)iz * BO_;
    const int brow = b0 + tb4 * 4;
    yp[(size_t)(brow + 0) * O_ + o0 + to] = NORM_ * acc0;
    yp[(size_t)(brow + 1) * O_ + o0 + to] = NORM_ * acc1;
    yp[(size_t)(brow + 2) * O_ + o0 + to] = NORM_ * acc2;
    yp[(size_t)(brow + 3) * O_ + o0 + to] = NORM_ * acc3;
}

// ---------------------------------------------------------------------------
// K2: fused i-partial combine + BatchNorm (stats + apply), one launch.
// 128 blocks x 256 threads; block owns 4 o-columns, full batch.
// ---------------------------------------------------------------------------
__global__ __launch_bounds__(256) void comb_bn(
    const float* __restrict__ pY,
    const float* __restrict__ gamma, const float* __restrict__ beta,
    float* __restrict__ y)
{
    __shared__ float Ws[4][8];   // per-wave partial {s4, q4}
    __shared__ float Ac[8];      // broadcast {a4, c4}

    const int t  = threadIdx.x;
    const int o4 = blockIdx.x * 4;

    // combine the 4 i-partials; accumulate column stats
    float4 v[2];
    float sx = 0.f, sy = 0.f, sz = 0.f, sw = 0.f;
    float qx = 0.f, qy = 0.f, qz = 0.f, qw = 0.f;
    #pragma unroll
    for (int r = 0; r < 2; ++r) {
        const int b = t + 256 * r;
        const size_t base = (size_t)b * O_ + o4;
        float4 a = *reinterpret_cast<const float4*>(&pY[base]);
        #pragma unroll
        for (int z = 1; z < ISPLIT; ++z) {
            const float4 p = *reinterpret_cast<const float4*>(&pY[(size_t)z * BO_ + base]);
            a.x += p.x; a.y += p.y; a.z += p.z; a.w += p.w;
        }
        v[r] = a;
        sx += a.x; sy += a.y; sz += a.z; sw += a.w;
        qx += a.x * a.x; qy += a.y * a.y; qz += a.z * a.z; qw += a.w * a.w;
    }

    // wave butterfly reduction (64 lanes)
    #pragma unroll
    for (int m = 1; m < 64; m <<= 1) {
        sx += __shfl_xor(sx, m); sy += __shfl_xor(sy, m);
        sz += __shfl_xor(sz, m); sw += __shfl_xor(sw, m);
        qx += __shfl_xor(qx, m); qy += __shfl_xor(qy, m);
        qz += __shfl_xor(qz, m); qw += __shfl_xor(qw, m);
    }
    if ((t & 63) == 0) {
        const int wv = t >> 6;
        Ws[wv][0] = sx; Ws[wv][1] = sy; Ws[wv][2] = sz; Ws[wv][3] = sw;
        Ws[wv][4] = qx; Ws[wv][5] = qy; Ws[wv][6] = qz; Ws[wv][7] = qw;
    }
    __syncthreads();
    if (t < 4) {
        const float s  = Ws[0][t]     + Ws[1][t]     + Ws[2][t]     + Ws[3][t];
        const float q  = Ws[0][t + 4] + Ws[1][t + 4] + Ws[2][t + 4] + Ws[3][t + 4];
        const float mean = s * (1.0f / B_);
        const float var  = q * (1.0f / B_) - mean * mean;
        const float inv  = rsqrtf(var + BN_EPS);
        const float a = gamma[o4 + t] * inv;
        Ac[t]     = a;
        Ac[t + 4] = fmaf(-mean, a, beta[o4 + t]);
    }
    __syncthreads();

    const float4 a4 = *reinterpret_cast<const float4*>(&Ac[0]);
    const float4 c4 = *reinterpret_cast<const float4*>(&Ac[4]);
    #pragma unroll
    for (int r = 0; r < 2; ++r) {
        const int b = t + 256 * r;
        float4 o;
        o.x = fmaf(v[r].x, a4.x, c4.x);
        o.y = fmaf(v[r].y, a4.y, c4.y);
        o.z = fmaf(v[r].z, a4.z, c4.z);
        o.w = fmaf(v[r].w, a4.w, c4.w);
        *reinterpret_cast<float4*>(&y[(size_t)b * O_ + o4]) = o;
    }
}

// ---------------------------------------------------------------------------
// Fallback path (Round-1 kernels, 32 KB ws) — used only if ws too small.
// ---------------------------------------------------------------------------
__global__ __launch_bounds__(256) void kan_main(
    const float* __restrict__ x, const float* __restrict__ scale,
    const float* __restrict__ bias, const float* __restrict__ weight,
    float* __restrict__ y, float* __restrict__ psum, float* __restrict__ psumsq)
{
    __shared__ float LxF[KI][LXS];
    __shared__ float Lp[KI][TO][4];
    __shared__ float Rs[2][TB/4][TO];

    const int t   = threadIdx.x;
    const int to  = t & (TO - 1);
    const int tb4 = t >> 4;
    const int o0  = blockIdx.x * TO;
    const int b0  = blockIdx.y * TB;
    const int lb = t >> 2;
    const int lq = t & 3;
    const int li = t >> 4;
    const int lo = t & 15;

    float acc0 = 0.f, acc1 = 0.f, acc2 = 0.f, acc3 = 0.f;

    for (int ch = 0; ch < NCH; ++ch) {
        const int i0 = ch * KI;
        const float4 xv = *reinterpret_cast<const float4*>(&x[(b0 + lb) * I_ + i0 + lq * 4]);
        const int pidx = (i0 + li) * O_ + o0 + lo;
        const float sc = scale[pidx];
        const float bi = bias[pidx];
        const float w  = weight[pidx];

        __syncthreads();
        LxF[lq * 4 + 0][lb] = xv.x;
        LxF[lq * 4 + 1][lb] = xv.y;
        LxF[lq * 4 + 2][lb] = xv.z;
        LxF[lq * 4 + 3][lb] = xv.w;
        const float rs = __builtin_amdgcn_rcpf(sc);
        Lp[li][lo][0] = rs;
        Lp[li][lo][1] = bi * rs;
        Lp[li][lo][2] = w;
        __syncthreads();

        #pragma unroll
        for (int ii = 0; ii < KI; ++ii) {
            const float4 p  = *reinterpret_cast<const float4*>(&Lp[ii][to][0]);
            const float4 xx = *reinterpret_cast<const float4*>(&LxF[ii][tb4 * 4]);
            {
                const float tt = fmaf(xx.x, p.x, -p.y);
                const float t2 = tt * tt;
                const float e  = EXP2F(t2 * K_EXP);
                const float g  = fmaf(t2, p.z, -p.z);
                acc0 = fmaf(g, e, acc0);
            }
            {
                const float tt = fmaf(xx.y, p.x, -p.y);
                const float t2 = tt * tt;
                const float e  = EXP2F(t2 * K_EXP);
                const float g  = fmaf(t2, p.z, -p.z);
                acc1 = fmaf(g, e, acc1);
            }
            {
                const float tt = fmaf(xx.z, p.x, -p.y);
                const float t2 = tt * tt;
                const float e  = EXP2F(t2 * K_EXP);
                const float g  = fmaf(t2, p.z, -p.z);
                acc2 = fmaf(g, e, acc2);
            }
            {
                const float tt = fmaf(xx.w, p.x, -p.y);
                const float t2 = tt * tt;
                const float e  = EXP2F(t2 * K_EXP);
                const float g  = fmaf(t2, p.z, -p.z);
                acc3 = fmaf(g, e, acc3);
            }
        }
    }

    const float y0 = NORM_ * acc0;
    const float y1 = NORM_ * acc1;
    const float y2 = NORM_ * acc2;
    const float y3 = NORM_ * acc3;

    const int brow = b0 + tb4 * 4;
    y[(brow + 0) * O_ + o0 + to] = y0;
    y[(brow + 1) * O_ + o0 + to] = y1;
    y[(brow + 2) * O_ + o0 + to] = y2;
    y[(brow + 3) * O_ + o0 + to] = y3;

    Rs[0][tb4][to] = y0 + y1 + y2 + y3;
    Rs[1][tb4][to] = y0 * y0 + y1 * y1 + y2 * y2 + y3 * y3;
    __syncthreads();
    if (t < TO) {
        float s = 0.f, s2 = 0.f;
        #pragma unroll
        for (int k = 0; k < TB / 4; ++k) {
            s  += Rs[0][k][t];
            s2 += Rs[1][k][t];
        }
        psum  [blockIdx.y * O_ + o0 + t] = s;
        psumsq[blockIdx.y * O_ + o0 + t] = s2;
    }
}

__global__ __launch_bounds__(256) void bn_apply(
    const float* __restrict__ psum, const float* __restrict__ psumsq,
    const float* __restrict__ gamma, const float* __restrict__ beta,
    float* __restrict__ y)
{
    const int o = blockIdx.x * 256 + threadIdx.x;
    float s = 0.f, s2 = 0.f;
    #pragma unroll
    for (int k = 0; k < B_ / TB; ++k) {
        s  += psum  [k * O_ + o];
        s2 += psumsq[k * O_ + o];
    }
    const float mean = s * (1.0f / B_);
    const float var  = s2 * (1.0f / B_) - mean * mean;
    const float inv  = rsqrtf(var + BN_EPS);
    const float a = gamma[o] * inv;
    const float c = fmaf(-mean, a, beta[o]);

    const int bstart = blockIdx.y * 16;
    #pragma unroll
    for (int b = bstart; b < bstart + 16; ++b) {
        const int idx = b * O_ + o;
        y[idx] = fmaf(y[idx], a, c);
    }
}

// ---------------------------------------------------------------------------

extern "C" void kernel_launch(void* const* d_in, const int* in_sizes, int n_in,
                              void* d_out, int out_size, void* d_ws, size_t ws_size,
                              hipStream_t stream) {
    const float* x      = (const float*)d_in[0];
    const float* scale  = (const float*)d_in[1];
    const float* bias   = (const float*)d_in[2];
    const float* weight = (const float*)d_in[3];
    const float* gamma  = (const float*)d_in[4];
    const float* beta   = (const float*)d_in[5];
    float* out = (float*)d_out;

    const size_t pY_b = (size_t)ISPLIT * BO_ * sizeof(float);   // 4 MB

    if (ws_size >= pY_b) {
        float* pY = (float*)d_ws;

        kan4<<<(O_ / TO) * (B_ / TB) * ISPLIT, 256, 0, stream>>>(   // 1024 blocks
            x, scale, bias, weight, pY);

        comb_bn<<<O_ / 4, 256, 0, stream>>>(pY, gamma, beta, out);  // 128 blocks
    } else {
        float* psum   = (float*)d_ws;
        float* psumsq = psum + (B_ / TB) * O_;

        dim3 g1(O_ / TO, B_ / TB);
        kan_main<<<g1, 256, 0, stream>>>(x, scale, bias, weight, out, psum, psumsq);

        dim3 g2(O_ / 256, B_ / 16);
        bn_apply<<<g2, 256, 0, stream>>>(psum, psumsq, gamma, beta, out);
    }
}